// Round 3
// baseline (1288.201 us; speedup 1.0000x reference)
//
#include <hip/hip_runtime.h>
#include <math.h>

#define NN 50000
#define NE 800000
#define NH 4
#define ND 64
#define NF 256
#define NEG_SLOPE 0.2f

__device__ __forceinline__ float elu1(float x) { return x > 0.f ? x : (expf(x) - 1.f); }
__device__ __forceinline__ float lrelu(float x) { return x > 0.f ? x : NEG_SLOPE * x; }

// f32 -> bf16 round-to-nearest-even
__device__ __forceinline__ unsigned short f2b(float x) {
    unsigned int u = __float_as_uint(x);
    u = (u + 0x7FFFu + ((u >> 16) & 1u)) >> 16;
    return (unsigned short)u;
}
__device__ __forceinline__ float b2f(unsigned short b) {
    return __uint_as_float(((unsigned int)b) << 16);
}
__device__ __forceinline__ float sel4(float a0, float a1, float a2, float a3, int h) {
    float r = a0;
    r = (h == 1) ? a1 : r;
    r = (h == 2) ? a2 : r;
    r = (h == 3) ? a3 : r;
    return r;
}

// ---------------- GEMM: Wh = h @ W, 64x64 tile; epilogue computes el/er (fp32)
// and stores Wh as bf16. blockIdx.y == head (64 cols per head).
__global__ __launch_bounds__(256) void gemm_fused(const float* __restrict__ A,
                                                  const float* __restrict__ B,
                                                  const float* __restrict__ al,
                                                  const float* __restrict__ ar,
                                                  unsigned short* __restrict__ Whb,
                                                  float* __restrict__ el,
                                                  float* __restrict__ er) {
    __shared__ float As[16][68];   // [k][m]
    __shared__ float Bs[16][68];   // [k][n]
    int t = threadIdx.x;
    int bm = blockIdx.x * 64;
    int bn = blockIdx.y * 64;
    int tx = t & 15, ty = t >> 4;
    float4 acc0 = {0,0,0,0}, acc1 = {0,0,0,0}, acc2 = {0,0,0,0}, acc3 = {0,0,0,0};
    for (int k0 = 0; k0 < 256; k0 += 16) {
        int i = t * 4;
        int arow = i >> 4, acol = i & 15;
        int gr = bm + arow;
        float4 av = {0,0,0,0};
        if (gr < NN) av = *(const float4*)&A[(size_t)gr * 256 + k0 + acol];
        As[acol + 0][arow] = av.x; As[acol + 1][arow] = av.y;
        As[acol + 2][arow] = av.z; As[acol + 3][arow] = av.w;
        int brow = i >> 6, bcol = i & 63;
        float4 bv = *(const float4*)&B[(size_t)(k0 + brow) * 256 + bn + bcol];
        *(float4*)&Bs[brow][bcol] = bv;
        __syncthreads();
        #pragma unroll
        for (int kk = 0; kk < 16; ++kk) {
            float4 b = *(float4*)&Bs[kk][tx * 4];
            float a0 = As[kk][ty * 4 + 0];
            float a1 = As[kk][ty * 4 + 1];
            float a2 = As[kk][ty * 4 + 2];
            float a3 = As[kk][ty * 4 + 3];
            acc0.x += a0 * b.x; acc0.y += a0 * b.y; acc0.z += a0 * b.z; acc0.w += a0 * b.w;
            acc1.x += a1 * b.x; acc1.y += a1 * b.y; acc1.z += a1 * b.z; acc1.w += a1 * b.w;
            acc2.x += a2 * b.x; acc2.y += a2 * b.y; acc2.z += a2 * b.z; acc2.w += a2 * b.w;
            acc3.x += a3 * b.x; acc3.y += a3 * b.y; acc3.z += a3 * b.z; acc3.w += a3 * b.w;
        }
        __syncthreads();
    }
    int h = blockIdx.y;
    int col = bn + tx * 4;
    float4 alv = *(const float4*)&al[h * 64 + tx * 4];
    float4 arv = *(const float4*)&ar[h * 64 + tx * 4];
    float4 accs[4] = {acc0, acc1, acc2, acc3};
    #pragma unroll
    for (int r = 0; r < 4; ++r) {
        float ep = accs[r].x * alv.x + accs[r].y * alv.y + accs[r].z * alv.z + accs[r].w * alv.w;
        float eq = accs[r].x * arv.x + accs[r].y * arv.y + accs[r].z * arv.z + accs[r].w * arv.w;
        #pragma unroll
        for (int msk = 1; msk < 16; msk <<= 1) {
            ep += __shfl_xor(ep, msk);
            eq += __shfl_xor(eq, msk);
        }
        int row = bm + ty * 4 + r;
        if (row < NN) {
            if (tx == 0) {
                el[row * 4 + h] = ep;
                er[row * 4 + h] = eq;
            }
            ushort4 o;
            o.x = f2b(accs[r].x); o.y = f2b(accs[r].y);
            o.z = f2b(accs[r].z); o.w = f2b(accs[r].w);
            *(ushort4*)&Whb[(size_t)row * 256 + col] = o;
        }
    }
}

// ---------------- CSR build
__global__ __launch_bounds__(256) void hist_kernel(const int* __restrict__ dst, int* __restrict__ deg) {
    int e = blockIdx.x * 256 + threadIdx.x;
    if (e < NE) atomicAdd(&deg[dst[e]], 1);
}

__global__ __launch_bounds__(1024) void scan_deg(const int* __restrict__ deg, int* __restrict__ rp) {
    __shared__ int tmp[1024];
    int t = threadIdx.x;
    int running = 0;
    for (int base = 0; base < NN; base += 1024) {
        int i = base + t;
        int v = (i < NN) ? deg[i] : 0;
        tmp[t] = v;
        __syncthreads();
        int x = v;
        #pragma unroll
        for (int off = 1; off < 1024; off <<= 1) {
            int add = (t >= off) ? tmp[t - off] : 0;
            __syncthreads();
            x += add;
            tmp[t] = x;
            __syncthreads();
        }
        if (i < NN) rp[i] = running + x - v;   // exclusive
        int total = tmp[1023];
        __syncthreads();
        running += total;
    }
    if (t == 0) rp[NN] = running;
}

__global__ __launch_bounds__(256) void copy_cursor(const int* __restrict__ rp, int* __restrict__ cur) {
    int i = blockIdx.x * 256 + threadIdx.x;
    if (i < NN) cur[i] = rp[i];
}

__global__ __launch_bounds__(256) void fill_kernel(const int* __restrict__ src,
                                                   const int* __restrict__ dst,
                                                   int* __restrict__ cur,
                                                   int* __restrict__ colv) {
    int e = blockIdx.x * 256 + threadIdx.x;
    if (e < NE) {
        int pos = atomicAdd(&cur[dst[e]], 1);
        colv[pos] = src[e];
    }
}

// ---------------- per-node fused: softmax over in-edges + gather-aggregate +
// bias + ELU + semantic projection w; path0 stores z0+w0, path1 combines into out.
// 8 waves/block, 1 node per wave. Wp1 cached in LDS as bf16 (64KB).
__global__ __launch_bounds__(512) void node_agg(const int* __restrict__ rp,
                                                const int* __restrict__ colv,
                                                const float* __restrict__ el,
                                                const float* __restrict__ er,
                                                const unsigned short* __restrict__ Whb,
                                                const float* __restrict__ bias,
                                                const float* __restrict__ Wp1,
                                                const float* __restrict__ bp1,
                                                const float* __restrict__ Wp2,
                                                float* __restrict__ w0,
                                                float* __restrict__ zio,
                                                int path) {
    __shared__ unsigned short wp1s[NF * 128];  // 64 KB, bf16 copy of Wp1
    __shared__ float zrow[8][256];             // 8 KB
    int t = threadIdx.x;
    for (int i = t; i < NF * 128; i += 512) wp1s[i] = f2b(Wp1[i]);

    int wid = t >> 6;
    int lane = t & 63;
    int n = blockIdx.x * 8 + wid;              // 6250*8 = 50000 exactly
    int beg = rp[n], end = rp[n + 1];
    int h = lane >> 4;
    float4 erv = *(const float4*)&er[(size_t)n * 4];

    // phase A: per-head max over in-edges
    float mx0 = -INFINITY, mx1 = -INFINITY, mx2 = -INFINITY, mx3 = -INFINITY;
    for (int j = beg + lane; j < end; j += 64) {
        int sidx = colv[j];
        float4 elv = *(const float4*)&el[(size_t)sidx * 4];
        mx0 = fmaxf(mx0, lrelu(elv.x + erv.x));
        mx1 = fmaxf(mx1, lrelu(elv.y + erv.y));
        mx2 = fmaxf(mx2, lrelu(elv.z + erv.z));
        mx3 = fmaxf(mx3, lrelu(elv.w + erv.w));
    }
    #pragma unroll
    for (int msk = 1; msk < 64; msk <<= 1) {
        mx0 = fmaxf(mx0, __shfl_xor(mx0, msk));
        mx1 = fmaxf(mx1, __shfl_xor(mx1, msk));
        mx2 = fmaxf(mx2, __shfl_xor(mx2, msk));
        mx3 = fmaxf(mx3, __shfl_xor(mx3, msk));
    }
    // phase B: per-head sum of exp
    float s0 = 0.f, s1 = 0.f, s2 = 0.f, s3 = 0.f;
    for (int j = beg + lane; j < end; j += 64) {
        int sidx = colv[j];
        float4 elv = *(const float4*)&el[(size_t)sidx * 4];
        s0 += expf(lrelu(elv.x + erv.x) - mx0);
        s1 += expf(lrelu(elv.y + erv.y) - mx1);
        s2 += expf(lrelu(elv.z + erv.z) - mx2);
        s3 += expf(lrelu(elv.w + erv.w) - mx3);
    }
    #pragma unroll
    for (int msk = 1; msk < 64; msk <<= 1) {
        s0 += __shfl_xor(s0, msk);
        s1 += __shfl_xor(s1, msk);
        s2 += __shfl_xor(s2, msk);
        s3 += __shfl_xor(s3, msk);
    }
    float m_h = sel4(mx0, mx1, mx2, mx3, h);
    float s_h = sel4(s0, s1, s2, s3, h);
    float er_h = sel4(erv.x, erv.y, erv.z, erv.w, h);
    float inv_s = 1.0f / s_h;                 // deg==0 -> inf, unused (loop empty)

    // phase C: weighted gather of bf16 Wh rows (lane owns 4 d's)
    float acc0 = 0.f, acc1 = 0.f, acc2 = 0.f, acc3 = 0.f;
    for (int j = beg; j < end; ++j) {
        int sidx = colv[j];
        float e = lrelu(el[(size_t)sidx * 4 + h] + er_h);
        float alpha = expf(e - m_h) * inv_s;
        ushort4 wv = *(const ushort4*)&Whb[(size_t)sidx * 256 + lane * 4];
        acc0 += alpha * b2f(wv.x);
        acc1 += alpha * b2f(wv.y);
        acc2 += alpha * b2f(wv.z);
        acc3 += alpha * b2f(wv.w);
    }
    float4 bv = *(const float4*)&bias[lane * 4];
    float z0 = elu1(acc0 + bv.x);
    float z1 = elu1(acc1 + bv.y);
    float z2 = elu1(acc2 + bv.z);
    float z3 = elu1(acc3 + bv.w);
    zrow[wid][lane * 4 + 0] = z0;
    zrow[wid][lane * 4 + 1] = z1;
    zrow[wid][lane * 4 + 2] = z2;
    zrow[wid][lane * 4 + 3] = z3;
    __syncthreads();   // covers wp1s (cross-wave) and zrow

    // semantic projection: lane handles k = 2*lane, 2*lane+1
    int k0 = 2 * lane;
    float a0 = 0.f, a1 = 0.f;
    for (int c = 0; c < 256; ++c) {
        float z = zrow[wid][c];
        unsigned int u = *(const unsigned int*)&wp1s[c * 128 + k0];
        a0 += z * __uint_as_float(u << 16);
        a1 += z * __uint_as_float(u & 0xFFFF0000u);
    }
    float v = tanhf(a0 + bp1[k0]) * Wp2[k0] + tanhf(a1 + bp1[k0 + 1]) * Wp2[k0 + 1];
    #pragma unroll
    for (int msk = 1; msk < 64; msk <<= 1) v += __shfl_xor(v, msk);

    if (path == 0) {
        float4 o = {z0, z1, z2, z3};
        *(float4*)&zio[(size_t)n * 256 + lane * 4] = o;
        if (lane == 0) w0[n] = v;
    } else {
        float wa = w0[n];
        float mw = fmaxf(wa, v);
        float ea = expf(wa - mw), eb = expf(v - mw);
        float inv = 1.f / (ea + eb);
        float beta0 = ea * inv, beta1 = eb * inv;
        float4 zp = *(const float4*)&zio[(size_t)n * 256 + lane * 4];
        float4 o;
        o.x = beta0 * zp.x + beta1 * z0;
        o.y = beta0 * zp.y + beta1 * z1;
        o.z = beta0 * zp.z + beta1 * z2;
        o.w = beta0 * zp.w + beta1 * z3;
        *(float4*)&zio[(size_t)n * 256 + lane * 4] = o;
    }
}

extern "C" void kernel_launch(void* const* d_in, const int* in_sizes, int n_in,
                              void* d_out, int out_size, void* d_ws, size_t ws_size,
                              hipStream_t stream) {
    const float* h   = (const float*)d_in[0];
    const int* src0  = (const int*)d_in[1];
    const int* dst0  = (const int*)d_in[2];
    const int* src1  = (const int*)d_in[3];
    const int* dst1  = (const int*)d_in[4];
    const float* W0  = (const float*)d_in[5];
    const float* al0 = (const float*)d_in[6];
    const float* ar0 = (const float*)d_in[7];
    const float* b0  = (const float*)d_in[8];
    const float* W1  = (const float*)d_in[9];
    const float* al1 = (const float*)d_in[10];
    const float* ar1 = (const float*)d_in[11];
    const float* b1  = (const float*)d_in[12];
    const float* Wp1 = (const float*)d_in[13];
    const float* bp1 = (const float*)d_in[14];
    const float* Wp2 = (const float*)d_in[15];

    // ws layout (~31.2 MB total)
    unsigned short* Whb = (unsigned short*)d_ws;               // NN*256 bf16 = 25.6 MB
    float* el  = (float*)(Whb + (size_t)NN * NF);              // NN*4
    float* er  = el + (size_t)NN * NH;                          // NN*4
    float* w0  = er + (size_t)NN * NH;                          // NN
    int*   deg = (int*)(w0 + NN);                               // NN
    int*   rp  = deg + NN;                                      // NN+1
    int*   cur = rp + NN + 1;                                   // NN
    int*   colv = cur + NN;                                     // NE
    float* zio = (float*)d_out;                                 // z0 then final out

    for (int p = 0; p < 2; ++p) {
        const int* src  = p ? src1 : src0;
        const int* dst  = p ? dst1 : dst0;
        const float* W  = p ? W1 : W0;
        const float* al = p ? al1 : al0;
        const float* ar = p ? ar1 : ar0;
        const float* bb = p ? b1 : b0;

        hipMemsetAsync(deg, 0, NN * sizeof(int), stream);
        hist_kernel<<<(NE + 255) / 256, 256, 0, stream>>>(dst, deg);
        scan_deg<<<1, 1024, 0, stream>>>(deg, rp);
        copy_cursor<<<(NN + 255) / 256, 256, 0, stream>>>(rp, cur);
        fill_kernel<<<(NE + 255) / 256, 256, 0, stream>>>(src, dst, cur, colv);
        gemm_fused<<<dim3((NN + 63) / 64, NH), 256, 0, stream>>>(h, W, al, ar, Whb, el, er);
        node_agg<<<NN / 8, 512, 0, stream>>>(rp, colv, el, er, Whb, bb, Wp1, bp1, Wp2,
                                             w0, zio, p);
    }
}

// Round 4
// 932.747 us; speedup vs baseline: 1.3811x; 1.3811x over previous
//
#include <hip/hip_runtime.h>
#include <math.h>

#define NN 50000
#define NE 800000
#define NH 4
#define ND 64
#define NF 256
#define NEG_SLOPE 0.2f

__device__ __forceinline__ float elu1(float x) { return x > 0.f ? x : (expf(x) - 1.f); }
__device__ __forceinline__ float lrelu(float x) { return x > 0.f ? x : NEG_SLOPE * x; }

// f32 -> bf16 round-to-nearest-even
__device__ __forceinline__ unsigned short f2b(float x) {
    unsigned int u = __float_as_uint(x);
    u = (u + 0x7FFFu + ((u >> 16) & 1u)) >> 16;
    return (unsigned short)u;
}
__device__ __forceinline__ float b2f(unsigned short b) {
    return __uint_as_float(((unsigned int)b) << 16);
}
__device__ __forceinline__ float blo(unsigned int u) { return __uint_as_float(u << 16); }
__device__ __forceinline__ float bhi(unsigned int u) { return __uint_as_float(u & 0xFFFF0000u); }
__device__ __forceinline__ float sel4(float a0, float a1, float a2, float a3, int h) {
    float r = a0;
    r = (h == 1) ? a1 : r;
    r = (h == 2) ? a2 : r;
    r = (h == 3) ? a3 : r;
    return r;
}

// ---------------- GEMM: Wh = h @ W, 64x64 tile; epilogue computes el/er (fp32)
// and stores Wh as bf16. blockIdx.y == head.
__global__ __launch_bounds__(256) void gemm_fused(const float* __restrict__ A,
                                                  const float* __restrict__ B,
                                                  const float* __restrict__ al,
                                                  const float* __restrict__ ar,
                                                  unsigned short* __restrict__ Whb,
                                                  float* __restrict__ el,
                                                  float* __restrict__ er) {
    __shared__ float As[16][68];   // [k][m]
    __shared__ float Bs[16][68];   // [k][n]
    int t = threadIdx.x;
    int bm = blockIdx.x * 64;
    int bn = blockIdx.y * 64;
    int tx = t & 15, ty = t >> 4;
    float4 acc0 = {0,0,0,0}, acc1 = {0,0,0,0}, acc2 = {0,0,0,0}, acc3 = {0,0,0,0};
    for (int k0 = 0; k0 < 256; k0 += 16) {
        int i = t * 4;
        int arow = i >> 4, acol = i & 15;
        int gr = bm + arow;
        float4 av = {0,0,0,0};
        if (gr < NN) av = *(const float4*)&A[(size_t)gr * 256 + k0 + acol];
        As[acol + 0][arow] = av.x; As[acol + 1][arow] = av.y;
        As[acol + 2][arow] = av.z; As[acol + 3][arow] = av.w;
        int brow = i >> 6, bcol = i & 63;
        float4 bv = *(const float4*)&B[(size_t)(k0 + brow) * 256 + bn + bcol];
        *(float4*)&Bs[brow][bcol] = bv;
        __syncthreads();
        #pragma unroll
        for (int kk = 0; kk < 16; ++kk) {
            float4 b = *(float4*)&Bs[kk][tx * 4];
            float a0 = As[kk][ty * 4 + 0];
            float a1 = As[kk][ty * 4 + 1];
            float a2 = As[kk][ty * 4 + 2];
            float a3 = As[kk][ty * 4 + 3];
            acc0.x += a0 * b.x; acc0.y += a0 * b.y; acc0.z += a0 * b.z; acc0.w += a0 * b.w;
            acc1.x += a1 * b.x; acc1.y += a1 * b.y; acc1.z += a1 * b.z; acc1.w += a1 * b.w;
            acc2.x += a2 * b.x; acc2.y += a2 * b.y; acc2.z += a2 * b.z; acc2.w += a2 * b.w;
            acc3.x += a3 * b.x; acc3.y += a3 * b.y; acc3.z += a3 * b.z; acc3.w += a3 * b.w;
        }
        __syncthreads();
    }
    int h = blockIdx.y;
    int col = bn + tx * 4;
    float4 alv = *(const float4*)&al[h * 64 + tx * 4];
    float4 arv = *(const float4*)&ar[h * 64 + tx * 4];
    float4 accs[4] = {acc0, acc1, acc2, acc3};
    #pragma unroll
    for (int r = 0; r < 4; ++r) {
        float ep = accs[r].x * alv.x + accs[r].y * alv.y + accs[r].z * alv.z + accs[r].w * alv.w;
        float eq = accs[r].x * arv.x + accs[r].y * arv.y + accs[r].z * arv.z + accs[r].w * arv.w;
        #pragma unroll
        for (int msk = 1; msk < 16; msk <<= 1) {
            ep += __shfl_xor(ep, msk);
            eq += __shfl_xor(eq, msk);
        }
        int row = bm + ty * 4 + r;
        if (row < NN) {
            if (tx == 0) {
                el[row * 4 + h] = ep;
                er[row * 4 + h] = eq;
            }
            ushort4 o;
            o.x = f2b(accs[r].x); o.y = f2b(accs[r].y);
            o.z = f2b(accs[r].z); o.w = f2b(accs[r].w);
            *(ushort4*)&Whb[(size_t)row * 256 + col] = o;
        }
    }
}

// ---------------- CSR build
__global__ __launch_bounds__(256) void hist_kernel(const int* __restrict__ dst, int* __restrict__ deg) {
    int e = blockIdx.x * 256 + threadIdx.x;
    if (e < NE) atomicAdd(&deg[dst[e]], 1);
}

// level-1: per-block (1024 elems) exclusive scan + block sums
__global__ __launch_bounds__(256) void scan_blk(const int* __restrict__ deg,
                                                int* __restrict__ rp,
                                                int* __restrict__ bsum) {
    __shared__ int ls[256];
    int b = blockIdx.x, t = threadIdx.x;
    int base = b * 1024 + t * 4;
    int v0 = (base + 0 < NN) ? deg[base + 0] : 0;
    int v1 = (base + 1 < NN) ? deg[base + 1] : 0;
    int v2 = (base + 2 < NN) ? deg[base + 2] : 0;
    int v3 = (base + 3 < NN) ? deg[base + 3] : 0;
    int p0 = v0, p1 = p0 + v1, p2 = p1 + v2, p3 = p2 + v3;
    ls[t] = p3;
    __syncthreads();
    int x = p3;
    #pragma unroll
    for (int off = 1; off < 256; off <<= 1) {
        int add = (t >= off) ? ls[t - off] : 0;
        __syncthreads();
        x += add;
        ls[t] = x;
        __syncthreads();
    }
    int excl = x - p3;
    if (base + 0 < NN) rp[base + 0] = excl;
    if (base + 1 < NN) rp[base + 1] = excl + p0;
    if (base + 2 < NN) rp[base + 2] = excl + p1;
    if (base + 3 < NN) rp[base + 3] = excl + p2;
    if (t == 255) bsum[b] = x;
}

// level-2: one wave scans the 49 block sums (exclusive), writes total to rp[NN]
__global__ __launch_bounds__(64) void scan_tops(int* __restrict__ bsum, int* __restrict__ rp, int nblk) {
    int t = threadIdx.x;
    int orig = (t < nblk) ? bsum[t] : 0;
    int v = orig;
    #pragma unroll
    for (int off = 1; off < 64; off <<= 1) {
        int y = __shfl_up(v, off);
        if (t >= off) v += y;
    }
    bsum[t] = v - orig;               // exclusive
    int total = __shfl(v, nblk - 1);
    if (t == 0) rp[NN] = total;
}

// level-3: add block offsets, emit cursor copy
__global__ __launch_bounds__(256) void scan_add(int* __restrict__ rp,
                                                const int* __restrict__ bsum,
                                                int* __restrict__ cur) {
    int i = blockIdx.x * 256 + threadIdx.x;
    if (i < NN) {
        int v = rp[i] + bsum[i >> 10];
        rp[i] = v;
        cur[i] = v;
    }
}

__global__ __launch_bounds__(256) void fill_kernel(const int* __restrict__ src,
                                                   const int* __restrict__ dst,
                                                   int* __restrict__ cur,
                                                   int* __restrict__ colv) {
    int e = blockIdx.x * 256 + threadIdx.x;
    if (e < NE) {
        int pos = atomicAdd(&cur[dst[e]], 1);
        colv[pos] = src[e];
    }
}

// ---------------- per-node fused kernel, v2.
// 8 waves/block, 1 node/wave. No segment-max (softmax shift-invariance; |e|<~6).
// Phase C: 4 edges in parallel (4 groups x 16 lanes, 16 dims/lane).
__global__ __launch_bounds__(512, 4) void node_agg(const int* __restrict__ rp,
                                                   const int* __restrict__ colv,
                                                   const float* __restrict__ el,
                                                   const float* __restrict__ er,
                                                   const unsigned short* __restrict__ Whb,
                                                   const float* __restrict__ bias,
                                                   const float* __restrict__ Wp1,
                                                   const float* __restrict__ bp1,
                                                   const float* __restrict__ Wp2,
                                                   float* __restrict__ w0,
                                                   float* __restrict__ zio,
                                                   int path) {
    __shared__ unsigned short wp1s[NF * 128];  // 64 KB bf16 Wp1
    __shared__ float zrow[8][256];             // 8 KB
    int t = threadIdx.x;
    for (int i = t; i < NF * 64; i += 512) {
        // vectorized bf16 conversion: 2 floats -> 1 uint
        float2 f = *(const float2*)&Wp1[i * 2];
        unsigned int u = ((unsigned int)f2b(f.y) << 16) | f2b(f.x);
        ((unsigned int*)wp1s)[i] = u;
    }

    int wid = t >> 6;
    int lane = t & 63;
    int n = blockIdx.x * 8 + wid;              // 6250*8 = 50000
    int beg = rp[n], end = rp[n + 1];
    float4 erv = *(const float4*)&er[(size_t)n * 4];

    // phase B: per-head sum of exp(e) over in-edges (edge-parallel over lanes)
    float s0 = 0.f, s1 = 0.f, s2 = 0.f, s3 = 0.f;
    for (int j = beg + lane; j < end; j += 64) {
        int sidx = colv[j];
        float4 elv = *(const float4*)&el[(size_t)sidx * 4];
        s0 += expf(lrelu(elv.x + erv.x));
        s1 += expf(lrelu(elv.y + erv.y));
        s2 += expf(lrelu(elv.z + erv.z));
        s3 += expf(lrelu(elv.w + erv.w));
    }
    #pragma unroll
    for (int msk = 1; msk < 64; msk <<= 1) {
        s0 += __shfl_xor(s0, msk);
        s1 += __shfl_xor(s1, msk);
        s2 += __shfl_xor(s2, msk);
        s3 += __shfl_xor(s3, msk);
    }
    float i0 = 1.f / s0, i1 = 1.f / s1, i2 = 1.f / s2, i3 = 1.f / s3;

    // phase C: 4 edge-groups x 16 lanes; lane owns dims [sl*16, sl*16+16)
    int eg = lane >> 4, sl = lane & 15;
    int h = sl >> 2;
    float er_h = sel4(erv.x, erv.y, erv.z, erv.w, h);
    float inv_h = sel4(i0, i1, i2, i3, h);
    float acc[16];
    #pragma unroll
    for (int i = 0; i < 16; ++i) acc[i] = 0.f;

    for (int j0 = beg; j0 < end; j0 += 4) {
        int j = j0 + eg;
        bool act = j < end;
        int sidx = colv[act ? j : beg];
        float e_l = el[(size_t)sidx * 4 + h];
        float a = expf(lrelu(e_l + er_h)) * inv_h;
        float alpha = act ? a : 0.f;
        const unsigned short* wr = &Whb[(size_t)sidx * 256 + sl * 16];
        uint4 u0 = *(const uint4*)wr;
        uint4 u1 = *(const uint4*)(wr + 8);
        acc[0]  += alpha * blo(u0.x); acc[1]  += alpha * bhi(u0.x);
        acc[2]  += alpha * blo(u0.y); acc[3]  += alpha * bhi(u0.y);
        acc[4]  += alpha * blo(u0.z); acc[5]  += alpha * bhi(u0.z);
        acc[6]  += alpha * blo(u0.w); acc[7]  += alpha * bhi(u0.w);
        acc[8]  += alpha * blo(u1.x); acc[9]  += alpha * bhi(u1.x);
        acc[10] += alpha * blo(u1.y); acc[11] += alpha * bhi(u1.y);
        acc[12] += alpha * blo(u1.z); acc[13] += alpha * bhi(u1.z);
        acc[14] += alpha * blo(u1.w); acc[15] += alpha * bhi(u1.w);
    }
    // reduce across the 4 edge-groups (lanes sl, sl+16, sl+32, sl+48)
    #pragma unroll
    for (int i = 0; i < 16; ++i) {
        acc[i] += __shfl_xor(acc[i], 16);
        acc[i] += __shfl_xor(acc[i], 32);
    }
    if (lane < 16) {
        #pragma unroll
        for (int i = 0; i < 16; ++i) {
            float z = elu1(acc[i] + bias[sl * 16 + i]);
            zrow[wid][sl * 16 + i] = z;
        }
    }
    __syncthreads();   // wp1s ready + zrow ready

    // semantic projection: lane handles k = 2*lane, 2*lane+1
    int k0 = 2 * lane;
    float a0 = 0.f, a1 = 0.f;
    #pragma unroll 4
    for (int c = 0; c < 256; ++c) {
        float z = zrow[wid][c];
        unsigned int u = *(const unsigned int*)&wp1s[c * 128 + k0];
        a0 += z * blo(u);
        a1 += z * bhi(u);
    }
    float v = tanhf(a0 + bp1[k0]) * Wp2[k0] + tanhf(a1 + bp1[k0 + 1]) * Wp2[k0 + 1];
    #pragma unroll
    for (int msk = 1; msk < 64; msk <<= 1) v += __shfl_xor(v, msk);

    float z0 = zrow[wid][lane * 4 + 0];
    float z1 = zrow[wid][lane * 4 + 1];
    float z2 = zrow[wid][lane * 4 + 2];
    float z3 = zrow[wid][lane * 4 + 3];
    if (path == 0) {
        float4 o = {z0, z1, z2, z3};
        *(float4*)&zio[(size_t)n * 256 + lane * 4] = o;
        if (lane == 0) w0[n] = v;
    } else {
        float wa = w0[n];
        float mw = fmaxf(wa, v);
        float ea = expf(wa - mw), eb = expf(v - mw);
        float inv = 1.f / (ea + eb);
        float beta0 = ea * inv, beta1 = eb * inv;
        float4 zp = *(const float4*)&zio[(size_t)n * 256 + lane * 4];
        float4 o;
        o.x = beta0 * zp.x + beta1 * z0;
        o.y = beta0 * zp.y + beta1 * z1;
        o.z = beta0 * zp.z + beta1 * z2;
        o.w = beta0 * zp.w + beta1 * z3;
        *(float4*)&zio[(size_t)n * 256 + lane * 4] = o;
    }
}

extern "C" void kernel_launch(void* const* d_in, const int* in_sizes, int n_in,
                              void* d_out, int out_size, void* d_ws, size_t ws_size,
                              hipStream_t stream) {
    const float* h   = (const float*)d_in[0];
    const int* src0  = (const int*)d_in[1];
    const int* dst0  = (const int*)d_in[2];
    const int* src1  = (const int*)d_in[3];
    const int* dst1  = (const int*)d_in[4];
    const float* W0  = (const float*)d_in[5];
    const float* al0 = (const float*)d_in[6];
    const float* ar0 = (const float*)d_in[7];
    const float* b0  = (const float*)d_in[8];
    const float* W1  = (const float*)d_in[9];
    const float* al1 = (const float*)d_in[10];
    const float* ar1 = (const float*)d_in[11];
    const float* b1  = (const float*)d_in[12];
    const float* Wp1 = (const float*)d_in[13];
    const float* bp1 = (const float*)d_in[14];
    const float* Wp2 = (const float*)d_in[15];

    // ws layout (~29.8 MB)
    unsigned short* Whb = (unsigned short*)d_ws;               // NN*256 bf16
    float* el  = (float*)(Whb + (size_t)NN * NF);              // NN*4
    float* er  = el + (size_t)NN * NH;
    float* w0  = er + (size_t)NN * NH;                          // NN
    int*   deg = (int*)(w0 + NN);                               // NN
    int*   rp  = deg + NN;                                      // NN+1
    int*   cur = rp + NN + 1;                                   // NN
    int*   colv = cur + NN;                                     // NE
    int*   bsum = colv + NE;                                    // 64
    float* zio = (float*)d_out;

    const int NBLK = (NN + 1023) / 1024;   // 49

    for (int p = 0; p < 2; ++p) {
        const int* src  = p ? src1 : src0;
        const int* dst  = p ? dst1 : dst0;
        const float* W  = p ? W1 : W0;
        const float* al = p ? al1 : al0;
        const float* ar = p ? ar1 : ar0;
        const float* bb = p ? b1 : b0;

        hipMemsetAsync(deg, 0, NN * sizeof(int), stream);
        hist_kernel<<<(NE + 255) / 256, 256, 0, stream>>>(dst, deg);
        scan_blk<<<NBLK, 256, 0, stream>>>(deg, rp, bsum);
        scan_tops<<<1, 64, 0, stream>>>(bsum, rp, NBLK);
        scan_add<<<(NN + 255) / 256, 256, 0, stream>>>(rp, bsum, cur);
        fill_kernel<<<(NE + 255) / 256, 256, 0, stream>>>(src, dst, cur, colv);
        gemm_fused<<<dim3((NN + 63) / 64, NH), 256, 0, stream>>>(h, W, al, ar, Whb, el, er);
        node_agg<<<NN / 8, 512, 0, stream>>>(rp, colv, el, er, Whb, bb, Wp1, bp1, Wp2,
                                             w0, zio, p);
    }
}

// Round 8
// 685.841 us; speedup vs baseline: 1.8783x; 1.3600x over previous
//
#include <hip/hip_runtime.h>
#include <math.h>

#define NN 50000
#define NE 800000
#define NH 4
#define ND 64
#define NF 256
#define NEG_SLOPE 0.2f

typedef __attribute__((ext_vector_type(8))) short s16x8;
typedef __attribute__((ext_vector_type(4))) float f32x4;

__device__ __forceinline__ float elu1(float x) { return x > 0.f ? x : (__expf(x) - 1.f); }
__device__ __forceinline__ float lrelu(float x) { return x > 0.f ? x : NEG_SLOPE * x; }

// f32 -> bf16 round-to-nearest-even (bit pattern)
__device__ __forceinline__ unsigned short f2b(float x) {
    unsigned int u = __float_as_uint(x);
    u = (u + 0x7FFFu + ((u >> 16) & 1u)) >> 16;
    return (unsigned short)u;
}
__device__ __forceinline__ float blo(unsigned int u) { return __uint_as_float(u << 16); }
__device__ __forceinline__ float bhi(unsigned int u) { return __uint_as_float(u & 0xFFFF0000u); }
__device__ __forceinline__ float sel4(float a0, float a1, float a2, float a3, int h) {
    float r = a0;
    r = (h == 1) ? a1 : r;
    r = (h == 2) ? a2 : r;
    r = (h == 3) ? a3 : r;
    return r;
}

// ---------------- prep: bf16 transposed weights.
// job 0/1: WT[n][k] = W[k][n]  (256x256); job 2: Wp1T[n][k] = Wp1[k][n] (128x256)
__global__ __launch_bounds__(256) void prep(const float* __restrict__ W0,
                                            const float* __restrict__ W1,
                                            const float* __restrict__ Wp1,
                                            short* __restrict__ WT0,
                                            short* __restrict__ WT1,
                                            short* __restrict__ Wp1T) {
    int t = threadIdx.x, b = blockIdx.x, job = blockIdx.y;
    if (job < 2) {
        const float* W = job ? W1 : W0;
        short* WT = job ? WT1 : WT0;
        WT[b * 256 + t] = (short)f2b(W[t * 256 + b]);
    } else if (b < 128) {
        Wp1T[b * 256 + t] = (short)f2b(Wp1[t * 128 + b]);
    }
}

// ---------------- MFMA GEMM: Wh = h @ W  (A fp32 converted in-register).
// Block = 256 thr = 4 waves; block covers rows m0..m0+15, wave = head (64 cols).
// Epilogue: Whb bf16 store + el/er via dot(al/ar) + shuffle reduce.
__global__ __launch_bounds__(256) void gemm_mfma(const float* __restrict__ A,
                                                 const short* __restrict__ WTb,
                                                 const float* __restrict__ al,
                                                 const float* __restrict__ ar,
                                                 unsigned short* __restrict__ Whb,
                                                 float* __restrict__ el,
                                                 float* __restrict__ er) {
    int t = threadIdx.x;
    int hh = t >> 6;          // wave = head
    int l = t & 63;
    int r16 = l & 15, kq = l >> 4;
    int m0 = blockIdx.x * 16;

    f32x4 acc[4] = {{0,0,0,0},{0,0,0,0},{0,0,0,0},{0,0,0,0}};
    const float* arow = A + (size_t)(m0 + r16) * 256;
    const short* bbase = WTb + (size_t)hh * 64 * 256;

    #pragma unroll
    for (int k0 = 0; k0 < 256; k0 += 32) {
        float4 f0 = *(const float4*)(arow + k0 + kq * 8);
        float4 f1 = *(const float4*)(arow + k0 + kq * 8 + 4);
        s16x8 af;
        af[0] = (short)f2b(f0.x); af[1] = (short)f2b(f0.y);
        af[2] = (short)f2b(f0.z); af[3] = (short)f2b(f0.w);
        af[4] = (short)f2b(f1.x); af[5] = (short)f2b(f1.y);
        af[6] = (short)f2b(f1.z); af[7] = (short)f2b(f1.w);
        #pragma unroll
        for (int nt = 0; nt < 4; ++nt) {
            s16x8 bf = *(const s16x8*)(bbase + (size_t)(nt * 16 + r16) * 256 + k0 + kq * 8);
            acc[nt] = __builtin_amdgcn_mfma_f32_16x16x32_bf16(af, bf, acc[nt], 0, 0, 0);
        }
    }

    // epilogue: D[row=(l>>4)*4+r][col=l&15] per nt-tile
    float elp[4] = {0,0,0,0}, erp[4] = {0,0,0,0};
    #pragma unroll
    for (int nt = 0; nt < 4; ++nt) {
        int col = nt * 16 + r16;               // 0..63 within head
        float alv = al[hh * 64 + col];
        float arv = ar[hh * 64 + col];
        #pragma unroll
        for (int r = 0; r < 4; ++r) {
            float v = acc[nt][r];
            int row = m0 + kq * 4 + r;
            Whb[(size_t)row * 256 + hh * 64 + col] = f2b(v);
            elp[r] += v * alv;
            erp[r] += v * arv;
        }
    }
    #pragma unroll
    for (int msk = 1; msk < 16; msk <<= 1) {
        #pragma unroll
        for (int r = 0; r < 4; ++r) {
            elp[r] += __shfl_xor(elp[r], msk);
            erp[r] += __shfl_xor(erp[r], msk);
        }
    }
    if (r16 == 0) {
        #pragma unroll
        for (int r = 0; r < 4; ++r) {
            int row = m0 + kq * 4 + r;
            el[row * 4 + hh] = elp[r];
            er[row * 4 + hh] = erp[r];
        }
    }
}

// ---------------- CSR build
__global__ __launch_bounds__(256) void hist_kernel(const int* __restrict__ dst, int* __restrict__ deg) {
    int e = blockIdx.x * 256 + threadIdx.x;
    if (e < NE) atomicAdd(&deg[dst[e]], 1);
}

__global__ __launch_bounds__(256) void scan_blk(const int* __restrict__ deg,
                                                int* __restrict__ rp,
                                                int* __restrict__ bsum) {
    __shared__ int ls[256];
    int b = blockIdx.x, t = threadIdx.x;
    int base = b * 1024 + t * 4;
    int v0 = (base + 0 < NN) ? deg[base + 0] : 0;
    int v1 = (base + 1 < NN) ? deg[base + 1] : 0;
    int v2 = (base + 2 < NN) ? deg[base + 2] : 0;
    int v3 = (base + 3 < NN) ? deg[base + 3] : 0;
    int p0 = v0, p1 = p0 + v1, p2 = p1 + v2, p3 = p2 + v3;
    ls[t] = p3;
    __syncthreads();
    int x = p3;
    #pragma unroll
    for (int off = 1; off < 256; off <<= 1) {
        int add = (t >= off) ? ls[t - off] : 0;
        __syncthreads();
        x += add;
        ls[t] = x;
        __syncthreads();
    }
    int excl = x - p3;
    if (base + 0 < NN) rp[base + 0] = excl;
    if (base + 1 < NN) rp[base + 1] = excl + p0;
    if (base + 2 < NN) rp[base + 2] = excl + p1;
    if (base + 3 < NN) rp[base + 3] = excl + p2;
    if (t == 255) bsum[b] = x;
}

__global__ __launch_bounds__(64) void scan_tops(int* __restrict__ bsum, int* __restrict__ rp, int nblk) {
    int t = threadIdx.x;
    int orig = (t < nblk) ? bsum[t] : 0;
    int v = orig;
    #pragma unroll
    for (int off = 1; off < 64; off <<= 1) {
        int y = __shfl_up(v, off);
        if (t >= off) v += y;
    }
    bsum[t] = v - orig;
    int total = __shfl(v, nblk - 1);
    if (t == 0) rp[NN] = total;
}

__global__ __launch_bounds__(256) void scan_add(int* __restrict__ rp,
                                                const int* __restrict__ bsum,
                                                int* __restrict__ cur) {
    int i = blockIdx.x * 256 + threadIdx.x;
    if (i < NN) {
        int v = rp[i] + bsum[i >> 10];
        rp[i] = v;
        cur[i] = v;
    }
}

__global__ __launch_bounds__(256) void fill_kernel(const int* __restrict__ src,
                                                   const int* __restrict__ dst,
                                                   int* __restrict__ cur,
                                                   int* __restrict__ colv) {
    int e = blockIdx.x * 256 + threadIdx.x;
    if (e < NE) {
        int pos = atomicAdd(&cur[dst[e]], 1);
        colv[pos] = src[e];
    }
}

// ---------------- node aggregation v3 (slim): one edge pass, unnormalized exp
// accumulation; z written bf16 to zb slot [n][path*256 .. +256).
__global__ __launch_bounds__(512) void node_agg(const int* __restrict__ rp,
                                                const int* __restrict__ colv,
                                                const float* __restrict__ el,
                                                const float* __restrict__ er,
                                                const unsigned short* __restrict__ Whb,
                                                const float* __restrict__ bias,
                                                unsigned short* __restrict__ zb,
                                                int path) {
    int t = threadIdx.x;
    int wid = t >> 6;
    int lane = t & 63;
    int n = blockIdx.x * 8 + wid;              // 6250*8 = 50000
    int beg = rp[n], end = rp[n + 1];
    float4 erv = *(const float4*)&er[(size_t)n * 4];

    int eg = lane >> 4, sl = lane & 15;
    int h = sl >> 2;
    float er_h = sel4(erv.x, erv.y, erv.z, erv.w, h);
    float acc[16];
    #pragma unroll
    for (int i = 0; i < 16; ++i) acc[i] = 0.f;
    float s = 0.f;

    for (int j0 = beg; j0 < end; j0 += 4) {
        int j = j0 + eg;
        bool act = j < end;
        int sidx = colv[act ? j : beg];
        float e_l = el[(size_t)sidx * 4 + h];
        float p = act ? __expf(lrelu(e_l + er_h)) : 0.f;
        s += p;
        const unsigned short* wr = &Whb[(size_t)sidx * 256 + sl * 16];
        uint4 u0 = *(const uint4*)wr;
        uint4 u1 = *(const uint4*)(wr + 8);
        acc[0]  += p * blo(u0.x); acc[1]  += p * bhi(u0.x);
        acc[2]  += p * blo(u0.y); acc[3]  += p * bhi(u0.y);
        acc[4]  += p * blo(u0.z); acc[5]  += p * bhi(u0.z);
        acc[6]  += p * blo(u0.w); acc[7]  += p * bhi(u0.w);
        acc[8]  += p * blo(u1.x); acc[9]  += p * bhi(u1.x);
        acc[10] += p * blo(u1.y); acc[11] += p * bhi(u1.y);
        acc[12] += p * blo(u1.z); acc[13] += p * bhi(u1.z);
        acc[14] += p * blo(u1.w); acc[15] += p * bhi(u1.w);
    }
    // reduce across the 4 edge-groups
    #pragma unroll
    for (int i = 0; i < 16; ++i) {
        acc[i] += __shfl_xor(acc[i], 16);
        acc[i] += __shfl_xor(acc[i], 32);
    }
    s += __shfl_xor(s, 16);
    s += __shfl_xor(s, 32);

    if (lane < 16) {
        float inv = (s > 0.f) ? 1.f / s : 0.f;
        unsigned int pk[8];
        #pragma unroll
        for (int i = 0; i < 8; ++i) {
            float za = elu1(acc[2 * i] * inv + bias[sl * 16 + 2 * i]);
            float zbv = elu1(acc[2 * i + 1] * inv + bias[sl * 16 + 2 * i + 1]);
            pk[i] = (unsigned int)f2b(za) | ((unsigned int)f2b(zbv) << 16);
        }
        unsigned int* op = (unsigned int*)(zb + (size_t)n * 512 + path * 256 + sl * 16);
        uint4 o0 = {pk[0], pk[1], pk[2], pk[3]};
        uint4 o1 = {pk[4], pk[5], pk[6], pk[7]};
        *(uint4*)op = o0;
        *(uint4*)(op + 4) = o1;
    }
}

// ---------------- semantic MFMA: w[row] for rows 0..99999 (z0 rows then z1 rows).
// zb layout: row n -> [n*512 + (path?256:0) .. +256) bf16, ld = 512.
__global__ __launch_bounds__(256) void semantic_mfma(const unsigned short* __restrict__ zb,
                                                     const short* __restrict__ Wp1T,
                                                     const float* __restrict__ bp1,
                                                     const float* __restrict__ Wp2,
                                                     float* __restrict__ w) {
    int t = threadIdx.x;
    int gw = blockIdx.x * 4 + (t >> 6);
    if (gw >= 6250) return;
    int l = t & 63;
    int r16 = l & 15, kq = l >> 4;
    int row0 = gw * 16;
    int path = (row0 >= NN) ? 1 : 0;
    int rbase = path ? row0 - NN : row0;
    const unsigned short* arow = zb + (size_t)(rbase + r16) * 512 + path * 256;

    f32x4 acc[8] = {{0,0,0,0},{0,0,0,0},{0,0,0,0},{0,0,0,0},
                    {0,0,0,0},{0,0,0,0},{0,0,0,0},{0,0,0,0}};
    #pragma unroll
    for (int k0 = 0; k0 < 256; k0 += 32) {
        s16x8 af = *(const s16x8*)(arow + k0 + kq * 8);
        #pragma unroll
        for (int nt = 0; nt < 8; ++nt) {
            s16x8 bf = *(const s16x8*)(Wp1T + (size_t)(nt * 16 + r16) * 256 + k0 + kq * 8);
            acc[nt] = __builtin_amdgcn_mfma_f32_16x16x32_bf16(af, bf, acc[nt], 0, 0, 0);
        }
    }
    float wpart[4] = {0,0,0,0};
    #pragma unroll
    for (int nt = 0; nt < 8; ++nt) {
        int col = nt * 16 + r16;
        float bpv = bp1[col], wpv = Wp2[col];
        #pragma unroll
        for (int r = 0; r < 4; ++r) wpart[r] += tanhf(acc[nt][r] + bpv) * wpv;
    }
    #pragma unroll
    for (int msk = 1; msk < 16; msk <<= 1) {
        #pragma unroll
        for (int r = 0; r < 4; ++r) wpart[r] += __shfl_xor(wpart[r], msk);
    }
    if (r16 == 0) {
        #pragma unroll
        for (int r = 0; r < 4; ++r) w[row0 + kq * 4 + r] = wpart[r];
    }
}

// ---------------- combine: beta softmax over 2 paths, rewrite d_out rows fp32.
// Block owns 4 rows (block-exclusive slots): stage reads -> sync -> write.
__global__ __launch_bounds__(256) void combine(float* __restrict__ zio,
                                               const float* __restrict__ w) {
    int n = blockIdx.x * 4 + (threadIdx.x >> 6);
    int c = (threadIdx.x & 63) * 4;
    const unsigned short* z0p = (const unsigned short*)zio + (size_t)n * 512 + c;
    uint2 u0 = *(const uint2*)z0p;
    uint2 u1 = *(const uint2*)(z0p + 256);
    float w0v = w[n], w1v = w[n + NN];
    __syncthreads();
    float mw = fmaxf(w0v, w1v);
    float e0 = __expf(w0v - mw), e1 = __expf(w1v - mw);
    float inv = 1.f / (e0 + e1);
    float b0 = e0 * inv, b1 = e1 * inv;
    float4 o;
    o.x = b0 * blo(u0.x) + b1 * blo(u1.x);
    o.y = b0 * bhi(u0.x) + b1 * bhi(u1.x);
    o.z = b0 * blo(u0.y) + b1 * blo(u1.y);
    o.w = b0 * bhi(u0.y) + b1 * bhi(u1.y);
    *(float4*)&zio[(size_t)n * 256 + c] = o;
}

extern "C" void kernel_launch(void* const* d_in, const int* in_sizes, int n_in,
                              void* d_out, int out_size, void* d_ws, size_t ws_size,
                              hipStream_t stream) {
    const float* h   = (const float*)d_in[0];
    const int* src0  = (const int*)d_in[1];
    const int* dst0  = (const int*)d_in[2];
    const int* src1  = (const int*)d_in[3];
    const int* dst1  = (const int*)d_in[4];
    const float* W0  = (const float*)d_in[5];
    const float* al0 = (const float*)d_in[6];
    const float* ar0 = (const float*)d_in[7];
    const float* b0  = (const float*)d_in[8];
    const float* W1  = (const float*)d_in[9];
    const float* al1 = (const float*)d_in[10];
    const float* ar1 = (const float*)d_in[11];
    const float* b1  = (const float*)d_in[12];
    const float* Wp1 = (const float*)d_in[13];
    const float* bp1 = (const float*)d_in[14];
    const float* Wp2 = (const float*)d_in[15];

    // ws layout (~32 MB)
    unsigned short* Whb = (unsigned short*)d_ws;                 // NN*256 bf16
    float* el  = (float*)(Whb + (size_t)NN * NF);                // NN*4
    float* er  = el + (size_t)NN * NH;                           // NN*4
    float* w   = er + (size_t)NN * NH;                           // 2*NN
    int*   deg = (int*)(w + 2 * NN);                             // NN
    int*   rp  = deg + NN;                                       // NN+1
    int*   cur = rp + NN + 1;                                    // NN
    int*   colv = cur + NN;                                      // NE
    int*   bsum = colv + NE;                                     // 64
    short* WT0 = (short*)(bsum + 64);                            // 256*256
    short* WT1 = WT0 + 256 * 256;                                // 256*256
    short* Wp1T = WT1 + 256 * 256;                               // 128*256
    unsigned short* zb = (unsigned short*)d_out;                 // [NN][512] bf16

    const int NBLK = (NN + 1023) / 1024;   // 49

    prep<<<dim3(256, 3), 256, 0, stream>>>(W0, W1, Wp1, WT0, WT1, Wp1T);

    for (int p = 0; p < 2; ++p) {
        const int* src  = p ? src1 : src0;
        const int* dst  = p ? dst1 : dst0;
        const float* al = p ? al1 : al0;
        const float* ar = p ? ar1 : ar0;
        const float* bb = p ? b1 : b0;
        const short* WT = p ? WT1 : WT0;

        hipMemsetAsync(deg, 0, NN * sizeof(int), stream);
        hist_kernel<<<(NE + 255) / 256, 256, 0, stream>>>(dst, deg);
        scan_blk<<<NBLK, 256, 0, stream>>>(deg, rp, bsum);
        scan_tops<<<1, 64, 0, stream>>>(bsum, rp, NBLK);
        scan_add<<<(NN + 255) / 256, 256, 0, stream>>>(rp, bsum, cur);
        fill_kernel<<<(NE + 255) / 256, 256, 0, stream>>>(src, dst, cur, colv);
        gemm_mfma<<<NN / 16, 256, 0, stream>>>(h, WT, al, ar, Whb, el, er);
        node_agg<<<NN / 8, 512, 0, stream>>>(rp, colv, el, er, Whb, bb, zb, p);
    }
    semantic_mfma<<<(6250 + 3) / 4, 256, 0, stream>>>(zb, Wp1T, bp1, Wp2, w);
    combine<<<NN / 4, 256, 0, stream>>>((float*)d_out, w);
}

// Round 10
// 635.275 us; speedup vs baseline: 2.0278x; 1.0796x over previous
//
#include <hip/hip_runtime.h>
#include <math.h>

#define NN 50000
#define NE 800000
#define NH 4
#define ND 64
#define NF 256
#define NEG_SLOPE 0.2f

typedef __attribute__((ext_vector_type(8))) short s16x8;
typedef __attribute__((ext_vector_type(4))) float f32x4;

__device__ __forceinline__ float elu1(float x) { return x > 0.f ? x : (__expf(x) - 1.f); }
__device__ __forceinline__ float lrelu(float x) { return x > 0.f ? x : NEG_SLOPE * x; }

// f32 -> bf16 round-to-nearest-even (bit pattern)
__device__ __forceinline__ unsigned short f2b(float x) {
    unsigned int u = __float_as_uint(x);
    u = (u + 0x7FFFu + ((u >> 16) & 1u)) >> 16;
    return (unsigned short)u;
}
__device__ __forceinline__ float blo(unsigned int u) { return __uint_as_float(u << 16); }
__device__ __forceinline__ float bhi(unsigned int u) { return __uint_as_float(u & 0xFFFF0000u); }
__device__ __forceinline__ float sel4(float a0, float a1, float a2, float a3, int h) {
    float r = a0;
    r = (h == 1) ? a1 : r;
    r = (h == 2) ? a2 : r;
    r = (h == 3) ? a3 : r;
    return r;
}

// ---------------- prep: bf16 transposed weights.
// job 0/1: WT[n][k] = W[k][n]  (256x256); job 2: Wp1T[n][k] = Wp1[k][n] (128x256)
__global__ __launch_bounds__(256) void prep(const float* __restrict__ W0,
                                            const float* __restrict__ W1,
                                            const float* __restrict__ Wp1,
                                            short* __restrict__ WT0,
                                            short* __restrict__ WT1,
                                            short* __restrict__ Wp1T) {
    int t = threadIdx.x, b = blockIdx.x, job = blockIdx.y;
    if (job < 2) {
        const float* W = job ? W1 : W0;
        short* WT = job ? WT1 : WT0;
        WT[b * 256 + t] = (short)f2b(W[t * 256 + b]);
    } else if (b < 128) {
        Wp1T[b * 256 + t] = (short)f2b(Wp1[t * 128 + b]);
    }
}

// ---------------- MFMA GEMM v2: Wh = h @ W. Block = 64 rows x 4 waves (wave = head).
// Per wave: 4 m-tiles x 4 n-tiles = 16 accumulators (4x ILP, B amortized).
// Epilogue: bf16 tile staged in padded LDS -> coalesced uint4 stores;
// el/er via dot(al/ar) + shuffle reduce.
__global__ __launch_bounds__(256) void gemm_mfma(const float* __restrict__ A,
                                                 const short* __restrict__ WTb,
                                                 const float* __restrict__ al,
                                                 const float* __restrict__ ar,
                                                 unsigned short* __restrict__ Whb,
                                                 float* __restrict__ el,
                                                 float* __restrict__ er) {
    __shared__ unsigned short st[4][16][72];   // per-wave staging, rows 144B (16B-aligned, bank-staggered)
    int t = threadIdx.x;
    int hh = t >> 6;          // wave = head
    int l = t & 63;
    int r16 = l & 15, kq = l >> 4;
    int m0 = blockIdx.x * 64;

    f32x4 acc[4][4];
    #pragma unroll
    for (int mt = 0; mt < 4; ++mt)
        #pragma unroll
        for (int nt = 0; nt < 4; ++nt)
            acc[mt][nt] = (f32x4){0.f, 0.f, 0.f, 0.f};

    const short* bbase = WTb + (size_t)hh * 64 * 256;
    const float* arow[4];
    #pragma unroll
    for (int mt = 0; mt < 4; ++mt) {
        int row = m0 + mt * 16 + r16;
        if (row > NN - 1) row = NN - 1;    // clamp (last block)
        arow[mt] = A + (size_t)row * 256;
    }

    #pragma unroll
    for (int k0 = 0; k0 < 256; k0 += 32) {
        s16x8 bf[4];
        #pragma unroll
        for (int nt = 0; nt < 4; ++nt)
            bf[nt] = *(const s16x8*)(bbase + (size_t)(nt * 16 + r16) * 256 + k0 + kq * 8);
        #pragma unroll
        for (int mt = 0; mt < 4; ++mt) {
            float4 f0 = *(const float4*)(arow[mt] + k0 + kq * 8);
            float4 f1 = *(const float4*)(arow[mt] + k0 + kq * 8 + 4);
            s16x8 af;
            af[0] = (short)f2b(f0.x); af[1] = (short)f2b(f0.y);
            af[2] = (short)f2b(f0.z); af[3] = (short)f2b(f0.w);
            af[4] = (short)f2b(f1.x); af[5] = (short)f2b(f1.y);
            af[6] = (short)f2b(f1.z); af[7] = (short)f2b(f1.w);
            #pragma unroll
            for (int nt = 0; nt < 4; ++nt)
                acc[mt][nt] = __builtin_amdgcn_mfma_f32_16x16x32_bf16(af, bf[nt], acc[mt][nt], 0, 0, 0);
        }
    }

    // el/er partials: D[row=kq*4+r][col=nt*16+r16]
    float elp[4][4], erp[4][4];
    #pragma unroll
    for (int mt = 0; mt < 4; ++mt)
        #pragma unroll
        for (int r = 0; r < 4; ++r) { elp[mt][r] = 0.f; erp[mt][r] = 0.f; }
    #pragma unroll
    for (int nt = 0; nt < 4; ++nt) {
        float alv = al[hh * 64 + nt * 16 + r16];
        float arv = ar[hh * 64 + nt * 16 + r16];
        #pragma unroll
        for (int mt = 0; mt < 4; ++mt)
            #pragma unroll
            for (int r = 0; r < 4; ++r) {
                float v = acc[mt][nt][r];
                elp[mt][r] += v * alv;
                erp[mt][r] += v * arv;
            }
    }
    #pragma unroll
    for (int msk = 1; msk < 16; msk <<= 1)
        #pragma unroll
        for (int mt = 0; mt < 4; ++mt)
            #pragma unroll
            for (int r = 0; r < 4; ++r) {
                elp[mt][r] += __shfl_xor(elp[mt][r], msk);
                erp[mt][r] += __shfl_xor(erp[mt][r], msk);
            }

    // staged coalesced Whb stores, one 16x64 tile at a time
    int srow = l >> 3;          // 0..7
    int chunk = l & 7;          // 0..7 (uint4 per 128B row)
    #pragma unroll
    for (int mt = 0; mt < 4; ++mt) {
        #pragma unroll
        for (int nt = 0; nt < 4; ++nt)
            #pragma unroll
            for (int r = 0; r < 4; ++r)
                st[hh][kq * 4 + r][nt * 16 + r16] = f2b(acc[mt][nt][r]);
        #pragma unroll
        for (int half = 0; half < 2; ++half) {
            int rr = srow + half * 8;
            int grow = m0 + mt * 16 + rr;
            uint4 v = *(const uint4*)&st[hh][rr][chunk * 8];
            if (grow < NN)
                *(uint4*)&Whb[(size_t)grow * 256 + hh * 64 + chunk * 8] = v;
        }
    }

    if (r16 == 0) {
        #pragma unroll
        for (int mt = 0; mt < 4; ++mt)
            #pragma unroll
            for (int r = 0; r < 4; ++r) {
                int row = m0 + mt * 16 + kq * 4 + r;
                if (row < NN) {
                    el[row * 4 + hh] = elp[mt][r];
                    er[row * 4 + hh] = erp[mt][r];
                }
            }
    }
}

// ---------------- CSR build
__global__ __launch_bounds__(256) void hist_kernel(const int* __restrict__ dst, int* __restrict__ deg) {
    int e = blockIdx.x * 256 + threadIdx.x;
    if (e < NE) atomicAdd(&deg[dst[e]], 1);
}

__global__ __launch_bounds__(256) void scan_blk(const int* __restrict__ deg,
                                                int* __restrict__ rp,
                                                int* __restrict__ bsum) {
    __shared__ int ls[256];
    int b = blockIdx.x, t = threadIdx.x;
    int base = b * 1024 + t * 4;
    int v0 = (base + 0 < NN) ? deg[base + 0] : 0;
    int v1 = (base + 1 < NN) ? deg[base + 1] : 0;
    int v2 = (base + 2 < NN) ? deg[base + 2] : 0;
    int v3 = (base + 3 < NN) ? deg[base + 3] : 0;
    int p0 = v0, p1 = p0 + v1, p2 = p1 + v2, p3 = p2 + v3;
    ls[t] = p3;
    __syncthreads();
    int x = p3;
    #pragma unroll
    for (int off = 1; off < 256; off <<= 1) {
        int add = (t >= off) ? ls[t - off] : 0;
        __syncthreads();
        x += add;
        ls[t] = x;
        __syncthreads();
    }
    int excl = x - p3;
    if (base + 0 < NN) rp[base + 0] = excl;
    if (base + 1 < NN) rp[base + 1] = excl + p0;
    if (base + 2 < NN) rp[base + 2] = excl + p1;
    if (base + 3 < NN) rp[base + 3] = excl + p2;
    if (t == 255) bsum[b] = x;
}

__global__ __launch_bounds__(64) void scan_tops(int* __restrict__ bsum, int* __restrict__ rp, int nblk) {
    int t = threadIdx.x;
    int orig = (t < nblk) ? bsum[t] : 0;
    int v = orig;
    #pragma unroll
    for (int off = 1; off < 64; off <<= 1) {
        int y = __shfl_up(v, off);
        if (t >= off) v += y;
    }
    bsum[t] = v - orig;
    int total = __shfl(v, nblk - 1);
    if (t == 0) rp[NN] = total;
}

__global__ __launch_bounds__(256) void scan_add(int* __restrict__ rp,
                                                const int* __restrict__ bsum,
                                                int* __restrict__ cur) {
    int i = blockIdx.x * 256 + threadIdx.x;
    if (i < NN) {
        int v = rp[i] + bsum[i >> 10];
        rp[i] = v;
        cur[i] = v;
    }
}

__global__ __launch_bounds__(256) void fill_kernel(const int* __restrict__ src,
                                                   const int* __restrict__ dst,
                                                   int* __restrict__ cur,
                                                   int* __restrict__ colv) {
    int e = blockIdx.x * 256 + threadIdx.x;
    if (e < NE) {
        int pos = atomicAdd(&cur[dst[e]], 1);
        colv[pos] = src[e];
    }
}

// ---------------- node aggregation v3 (slim): one edge pass, unnormalized exp
// accumulation; z written bf16 to zb slot [n][path*256 .. +256).
__global__ __launch_bounds__(512) void node_agg(const int* __restrict__ rp,
                                                const int* __restrict__ colv,
                                                const float* __restrict__ el,
                                                const float* __restrict__ er,
                                                const unsigned short* __restrict__ Whb,
                                                const float* __restrict__ bias,
                                                unsigned short* __restrict__ zb,
                                                int path) {
    int t = threadIdx.x;
    int wid = t >> 6;
    int lane = t & 63;
    int n = blockIdx.x * 8 + wid;              // 6250*8 = 50000
    int beg = rp[n], end = rp[n + 1];
    float4 erv = *(const float4*)&er[(size_t)n * 4];

    int eg = lane >> 4, sl = lane & 15;
    int h = sl >> 2;
    float er_h = sel4(erv.x, erv.y, erv.z, erv.w, h);
    float acc[16];
    #pragma unroll
    for (int i = 0; i < 16; ++i) acc[i] = 0.f;
    float s = 0.f;

    for (int j0 = beg; j0 < end; j0 += 4) {
        int j = j0 + eg;
        bool act = j < end;
        int sidx = colv[act ? j : beg];
        float e_l = el[(size_t)sidx * 4 + h];
        float p = act ? __expf(lrelu(e_l + er_h)) : 0.f;
        s += p;
        const unsigned short* wr = &Whb[(size_t)sidx * 256 + sl * 16];
        uint4 u0 = *(const uint4*)wr;
        uint4 u1 = *(const uint4*)(wr + 8);
        acc[0]  += p * blo(u0.x); acc[1]  += p * bhi(u0.x);
        acc[2]  += p * blo(u0.y); acc[3]  += p * bhi(u0.y);
        acc[4]  += p * blo(u0.z); acc[5]  += p * bhi(u0.z);
        acc[6]  += p * blo(u0.w); acc[7]  += p * bhi(u0.w);
        acc[8]  += p * blo(u1.x); acc[9]  += p * bhi(u1.x);
        acc[10] += p * blo(u1.y); acc[11] += p * bhi(u1.y);
        acc[12] += p * blo(u1.z); acc[13] += p * bhi(u1.z);
        acc[14] += p * blo(u1.w); acc[15] += p * bhi(u1.w);
    }
    // reduce across the 4 edge-groups
    #pragma unroll
    for (int i = 0; i < 16; ++i) {
        acc[i] += __shfl_xor(acc[i], 16);
        acc[i] += __shfl_xor(acc[i], 32);
    }
    s += __shfl_xor(s, 16);
    s += __shfl_xor(s, 32);

    if (lane < 16) {
        float inv = (s > 0.f) ? 1.f / s : 0.f;
        unsigned int pk[8];
        #pragma unroll
        for (int i = 0; i < 8; ++i) {
            float za = elu1(acc[2 * i] * inv + bias[sl * 16 + 2 * i]);
            float zbv = elu1(acc[2 * i + 1] * inv + bias[sl * 16 + 2 * i + 1]);
            pk[i] = (unsigned int)f2b(za) | ((unsigned int)f2b(zbv) << 16);
        }
        unsigned int* op = (unsigned int*)(zb + (size_t)n * 512 + path * 256 + sl * 16);
        uint4 o0 = {pk[0], pk[1], pk[2], pk[3]};
        uint4 o1 = {pk[4], pk[5], pk[6], pk[7]};
        *(uint4*)op = o0;
        *(uint4*)(op + 4) = o1;
    }
}

// ---------------- semantic MFMA: w[row] for rows 0..99999 (z0 rows then z1 rows).
// zb layout: row n -> [n*512 + (path?256:0) .. +256) bf16, ld = 512.
__global__ __launch_bounds__(256) void semantic_mfma(const unsigned short* __restrict__ zb,
                                                     const short* __restrict__ Wp1T,
                                                     const float* __restrict__ bp1,
                                                     const float* __restrict__ Wp2,
                                                     float* __restrict__ w) {
    int t = threadIdx.x;
    int gw = blockIdx.x * 4 + (t >> 6);
    if (gw >= 6250) return;
    int l = t & 63;
    int r16 = l & 15, kq = l >> 4;
    int row0 = gw * 16;
    int path = (row0 >= NN) ? 1 : 0;
    int rbase = path ? row0 - NN : row0;
    const unsigned short* arow = zb + (size_t)(rbase + r16) * 512 + path * 256;

    f32x4 acc[8] = {{0,0,0,0},{0,0,0,0},{0,0,0,0},{0,0,0,0},
                    {0,0,0,0},{0,0,0,0},{0,0,0,0},{0,0,0,0}};
    #pragma unroll
    for (int k0 = 0; k0 < 256; k0 += 32) {
        s16x8 af = *(const s16x8*)(arow + k0 + kq * 8);
        #pragma unroll
        for (int nt = 0; nt < 8; ++nt) {
            s16x8 bf = *(const s16x8*)(Wp1T + (size_t)(nt * 16 + r16) * 256 + k0 + kq * 8);
            acc[nt] = __builtin_amdgcn_mfma_f32_16x16x32_bf16(af, bf, acc[nt], 0, 0, 0);
        }
    }
    float wpart[4] = {0,0,0,0};
    #pragma unroll
    for (int nt = 0; nt < 8; ++nt) {
        int col = nt * 16 + r16;
        float bpv = bp1[col], wpv = Wp2[col];
        #pragma unroll
        for (int r = 0; r < 4; ++r) wpart[r] += tanhf(acc[nt][r] + bpv) * wpv;
    }
    #pragma unroll
    for (int msk = 1; msk < 16; msk <<= 1) {
        #pragma unroll
        for (int r = 0; r < 4; ++r) wpart[r] += __shfl_xor(wpart[r], msk);
    }
    if (r16 == 0) {
        #pragma unroll
        for (int r = 0; r < 4; ++r) w[row0 + kq * 4 + r] = wpart[r];
    }
}

// ---------------- combine: beta softmax over 2 paths, rewrite d_out rows fp32.
// Block owns 4 rows (block-exclusive slots): stage reads -> sync -> write.
__global__ __launch_bounds__(256) void combine(float* __restrict__ zio,
                                               const float* __restrict__ w) {
    int n = blockIdx.x * 4 + (threadIdx.x >> 6);
    int c = (threadIdx.x & 63) * 4;
    const unsigned short* z0p = (const unsigned short*)zio + (size_t)n * 512 + c;
    uint2 u0 = *(const uint2*)z0p;
    uint2 u1 = *(const uint2*)(z0p + 256);
    float w0v = w[n], w1v = w[n + NN];
    __syncthreads();
    float mw = fmaxf(w0v, w1v);
    float e0 = __expf(w0v - mw), e1 = __expf(w1v - mw);
    float inv = 1.f / (e0 + e1);
    float b0 = e0 * inv, b1 = e1 * inv;
    float4 o;
    o.x = b0 * blo(u0.x) + b1 * blo(u1.x);
    o.y = b0 * bhi(u0.x) + b1 * bhi(u1.x);
    o.z = b0 * blo(u0.y) + b1 * blo(u1.y);
    o.w = b0 * bhi(u0.y) + b1 * bhi(u1.y);
    *(float4*)&zio[(size_t)n * 256 + c] = o;
}

extern "C" void kernel_launch(void* const* d_in, const int* in_sizes, int n_in,
                              void* d_out, int out_size, void* d_ws, size_t ws_size,
                              hipStream_t stream) {
    const float* h   = (const float*)d_in[0];
    const int* src0  = (const int*)d_in[1];
    const int* dst0  = (const int*)d_in[2];
    const int* src1  = (const int*)d_in[3];
    const int* dst1  = (const int*)d_in[4];
    const float* W0  = (const float*)d_in[5];
    const float* al0 = (const float*)d_in[6];
    const float* ar0 = (const float*)d_in[7];
    const float* b0  = (const float*)d_in[8];
    const float* W1  = (const float*)d_in[9];
    const float* al1 = (const float*)d_in[10];
    const float* ar1 = (const float*)d_in[11];
    const float* b1  = (const float*)d_in[12];
    const float* Wp1 = (const float*)d_in[13];
    const float* bp1 = (const float*)d_in[14];
    const float* Wp2 = (const float*)d_in[15];

    // ws layout (~32 MB)
    unsigned short* Whb = (unsigned short*)d_ws;                 // NN*256 bf16
    float* el  = (float*)(Whb + (size_t)NN * NF);                // NN*4
    float* er  = el + (size_t)NN * NH;                           // NN*4
    float* w   = er + (size_t)NN * NH;                           // 2*NN
    int*   deg = (int*)(w + 2 * NN);                             // NN
    int*   rp  = deg + NN;                                       // NN+1
    int*   cur = rp + NN + 1;                                    // NN
    int*   colv = cur + NN;                                      // NE
    int*   bsum = colv + NE;                                     // 64
    short* WT0 = (short*)(bsum + 64);                            // 256*256
    short* WT1 = WT0 + 256 * 256;                                // 256*256
    short* Wp1T = WT1 + 256 * 256;                               // 128*256
    unsigned short* zb = (unsigned short*)d_out;                 // [NN][512] bf16

    const int NBLK = (NN + 1023) / 1024;   // 49

    prep<<<dim3(256, 3), 256, 0, stream>>>(W0, W1, Wp1, WT0, WT1, Wp1T);

    for (int p = 0; p < 2; ++p) {
        const int* src  = p ? src1 : src0;
        const int* dst  = p ? dst1 : dst0;
        const float* al = p ? al1 : al0;
        const float* ar = p ? ar1 : ar0;
        const float* bb = p ? b1 : b0;
        const short* WT = p ? WT1 : WT0;

        hipMemsetAsync(deg, 0, NN * sizeof(int), stream);
        hist_kernel<<<(NE + 255) / 256, 256, 0, stream>>>(dst, deg);
        scan_blk<<<NBLK, 256, 0, stream>>>(deg, rp, bsum);
        scan_tops<<<1, 64, 0, stream>>>(bsum, rp, NBLK);
        scan_add<<<(NN + 255) / 256, 256, 0, stream>>>(rp, bsum, cur);
        fill_kernel<<<(NE + 255) / 256, 256, 0, stream>>>(src, dst, cur, colv);
        gemm_mfma<<<(NN + 63) / 64, 256, 0, stream>>>(h, WT, al, ar, Whb, el, er);
        node_agg<<<NN / 8, 512, 0, stream>>>(rp, colv, el, er, Whb, bb, zb, p);
    }
    semantic_mfma<<<(6250 + 3) / 4, 256, 0, stream>>>(zb, Wp1T, bp1, Wp2, w);
    combine<<<NN / 4, 256, 0, stream>>>((float*)d_out, w);
}